// Round 8
// baseline (340.035 us; speedup 1.0000x reference)
//
#include <hip/hip_runtime.h>
#include <math.h>

typedef __attribute__((ext_vector_type(8))) short short8;   // 8 bf16 (4 VGPRs)
typedef __attribute__((ext_vector_type(4))) float f32x4;    // MFMA accumulator

constexpr int kD   = 2048;
constexpr int kE   = 64;
constexpr int kM   = 16;          // tokens per block -> 1024 blocks
constexpr int kCPW = 16;          // k-chunks per wave (K-split: 4 waves x 16 x K=32)

// p limbs in MFMA B-fragment order, CHUNK-MAJOR:
// g_B[((gc*4 + e0)*3 + plane)*512 + Lr*8 + j],  Lr = 16*((k>>3)&3) + (e&15)
// chunk block = 12 KB; each wave streams its 16-chunk range sequentially.
__device__ unsigned short g_B[64 * 4 * 3 * 512];   // 786 KB, L2-resident

// 3-limb truncated bf16 split: v = h + m + l + O(2^-24 |v|)
__device__ __forceinline__ void split3(float v, unsigned& h, unsigned& m, unsigned& l) {
  unsigned u = __float_as_uint(v);
  h = u & 0xFFFF0000u;
  float r1 = v - __uint_as_float(h);
  m = __float_as_uint(r1) & 0xFFFF0000u;
  float r2 = r1 - __uint_as_float(m);
  l = __float_as_uint(r2);
}

__device__ __forceinline__ void pack2(float e0, float e1,
                                      unsigned& dh, unsigned& dm, unsigned& dl) {
  unsigned h0, m0, l0, h1, m1, l1;
  split3(e0, h0, m0, l0);
  split3(e1, h1, m1, l1);
  dh = (h0 >> 16) | h1;
  dm = (m0 >> 16) | m1;
  dl = (l0 >> 16) | (l1 & 0xFFFF0000u);
}

union FragU { short8 s; unsigned u[4]; };

// ---------------------------------------------------------------------------
// Prep: S_e, inv_norm_e into ws; p 3-limb bf16 into g_B (chunk-major).
// ---------------------------------------------------------------------------
__global__ __launch_bounds__(256) void proto_prep(const float* __restrict__ p,
                                                  float* __restrict__ ws) {
  const int e = blockIdx.x, t = threadIdx.x;
  const float* row = p + (size_t)e * kD;
  float4 v0 = *(const float4*)(row + 8 * t);
  float4 v1 = *(const float4*)(row + 8 * t + 4);

  unsigned dh[4], dm[4], dl[4];
  pack2(v0.x, v0.y, dh[0], dm[0], dl[0]);
  pack2(v0.z, v0.w, dh[1], dm[1], dl[1]);
  pack2(v1.x, v1.y, dh[2], dm[2], dl[2]);
  pack2(v1.z, v1.w, dh[3], dm[3], dl[3]);
  const int gc = t >> 2, o = t & 3;
  const int Lr = 16 * o + (e & 15);
  size_t cb = (size_t)((gc * 4 + (e >> 4)) * 3) * 512 + Lr * 8;
  *(uint4*)&g_B[cb]        = make_uint4(dh[0], dh[1], dh[2], dh[3]);   // plane h
  *(uint4*)&g_B[cb + 512]  = make_uint4(dm[0], dm[1], dm[2], dm[3]);   // plane m
  *(uint4*)&g_B[cb + 1024] = make_uint4(dl[0], dl[1], dl[2], dl[3]);   // plane l

  float s = (v0.x + v0.y) + (v0.z + v0.w) + (v1.x + v1.y) + (v1.z + v1.w);
  float q = v0.x*v0.x + v0.y*v0.y + v0.z*v0.z + v0.w*v0.w
          + v1.x*v1.x + v1.y*v1.y + v1.z*v1.z + v1.w*v1.w;
  #pragma unroll
  for (int off = 32; off >= 1; off >>= 1) {
    s += __shfl_xor(s, off, 64);
    q += __shfl_xor(q, off, 64);
  }
  __shared__ float as[4], aq[4];
  if ((t & 63) == 0) { as[t >> 6] = s; aq[t >> 6] = q; }
  __syncthreads();
  if (t == 0) {
    float S = (as[0] + as[1]) + (as[2] + as[3]);
    float Q = (aq[0] + aq[1]) + (aq[2] + aq[3]);
    ws[e]      = S;
    ws[kE + e] = 1.f / fmaxf(sqrtf(Q), 1e-8f);
  }
}

// ---------------------------------------------------------------------------
// Main: 16 tokens/block, 4 waves K-SPLIT (16 chunks each), barrier-free
// K-loop. A direct from global x in MFMA layout; B streamed chunk-major from
// L2-hot g_B. 16 waves/CU for latency hiding. Two barriers total (epilogue).
// ---------------------------------------------------------------------------
__global__ __launch_bounds__(256, 4) void router_main(
    const float* __restrict__ x, const float* __restrict__ ws,
    float* __restrict__ out_w, float* __restrict__ out_i) {
  __shared__ f32x4 lacc[4][4][64];      // [kw][g][srcLane]  16384 B
  __shared__ float sLogit[kM * 68];     //  4352 B
  __shared__ float sSxP[4][kM];         //   256 B
  __shared__ float sSxxP[4][kM];        //   256 B   -> ~21 KB

  const int t    = threadIdx.x;
  const int w    = t >> 6;          // wave id = K-slice owner (chunks [16w,16w+16))
  const int L    = t & 63;
  const int ln15 = L & 15;
  const int q    = L >> 4;
  const int tok0 = blockIdx.x * kM;

  // A-frag: lane L -> token tok0+ln15, k = (16w+gc)*32 + q*8 + j
  const float* xa = x + (size_t)(tok0 + ln15) * kD + (size_t)w * kCPW * 32 + q * 8;
  // B-frag: wave w starts at chunk 16w; chunk stride 6144 ushorts (12 KB)
  const unsigned short* bb = g_B + (size_t)w * kCPW * 6144 + L * 8;

  f32x4 acc[4];
  #pragma unroll
  for (int g = 0; g < 4; ++g) acc[g] = (f32x4){0.f, 0.f, 0.f, 0.f};
  float sx = 0.f, sxx = 0.f;

  // register pipelines: x depth-2, B double-buffer depth-1
  float4 xv[2][2];
  short8 bv[2][12];
  #pragma unroll
  for (int c = 0; c < 2; ++c) {
    xv[c][0] = *(const float4*)(xa + c * 32);
    xv[c][1] = *(const float4*)(xa + c * 32 + 4);
  }
  #pragma unroll
  for (int gp = 0; gp < 12; ++gp) bv[0][gp] = *(const short8*)(bb + gp * 512);

  #pragma unroll 2
  for (int gc = 0; gc < kCPW; ++gc) {
    const int cur = gc & 1;
    float4 a0 = xv[cur][0], a1 = xv[cur][1];
    if (gc + 2 < kCPW) {                      // x prefetch, depth 2 (HBM)
      xv[cur][0] = *(const float4*)(xa + (gc + 2) * 32);
      xv[cur][1] = *(const float4*)(xa + (gc + 2) * 32 + 4);
    }
    if (gc + 1 < kCPW) {                      // B prefetch, depth 1 (L2 stream)
      const unsigned short* nb = bb + (size_t)(gc + 1) * 6144;
      #pragma unroll
      for (int gp = 0; gp < 12; ++gp) bv[cur ^ 1][gp] = *(const short8*)(nb + gp * 512);
    }
    // LN stats partials (lane's token, its k-slice)
    sx += (a0.x + a0.y) + (a0.z + a0.w) + (a1.x + a1.y) + (a1.z + a1.w);
    sxx = fmaf(a0.x, a0.x, fmaf(a0.y, a0.y, fmaf(a0.z, a0.z, fmaf(a0.w, a0.w, sxx))));
    sxx = fmaf(a1.x, a1.x, fmaf(a1.y, a1.y, fmaf(a1.z, a1.z, fmaf(a1.w, a1.w, sxx))));
    // 3-limb A pack, in-register
    FragU ah, am, al;
    pack2(a0.x, a0.y, ah.u[0], am.u[0], al.u[0]);
    pack2(a0.z, a0.w, ah.u[1], am.u[1], al.u[1]);
    pack2(a1.x, a1.y, ah.u[2], am.u[2], al.u[2]);
    pack2(a1.z, a1.w, ah.u[3], am.u[3], al.u[3]);
    #pragma unroll
    for (int g = 0; g < 4; ++g) {
      short8 bh = bv[cur][g * 3], bm = bv[cur][g * 3 + 1], bl = bv[cur][g * 3 + 2];
      // 6 limb products: hh, hm, mh, mm, hl, lh (dropped terms <= 2^-24)
      acc[g] = __builtin_amdgcn_mfma_f32_16x16x32_bf16(ah.s, bh, acc[g], 0, 0, 0);
      acc[g] = __builtin_amdgcn_mfma_f32_16x16x32_bf16(ah.s, bm, acc[g], 0, 0, 0);
      acc[g] = __builtin_amdgcn_mfma_f32_16x16x32_bf16(am.s, bh, acc[g], 0, 0, 0);
      acc[g] = __builtin_amdgcn_mfma_f32_16x16x32_bf16(am.s, bm, acc[g], 0, 0, 0);
      acc[g] = __builtin_amdgcn_mfma_f32_16x16x32_bf16(ah.s, bl, acc[g], 0, 0, 0);
      acc[g] = __builtin_amdgcn_mfma_f32_16x16x32_bf16(al.s, bh, acc[g], 0, 0, 0);
    }
  }

  // phase 1: deposit K-partials. stats: reduce over q (lanes sharing token)
  sx  += __shfl_xor(sx, 16, 64);  sx  += __shfl_xor(sx, 32, 64);
  sxx += __shfl_xor(sxx, 16, 64); sxx += __shfl_xor(sxx, 32, 64);
  if (L < 16) { sSxP[w][L] = sx; sSxxP[w][L] = sxx; }
  #pragma unroll
  for (int g = 0; g < 4; ++g) lacc[w][g][L] = acc[g];
  __syncthreads();

  // phase 2: thread (w,L) combines expert e = w*16+ln15, tokens q*4+i
  {
    f32x4 s = lacc[0][w][L];
    #pragma unroll
    for (int kw = 1; kw < 4; ++kw) {
      f32x4 v = lacc[kw][w][L];
      s[0] += v[0]; s[1] += v[1]; s[2] += v[2]; s[3] += v[3];
    }
    #pragma unroll
    for (int i = 0; i < 4; ++i)
      sLogit[(q * 4 + i) * 68 + w * 16 + ln15] = s[i];
  }
  __syncthreads();

  // phase 3 (verified R5 epilogue): wave w -> tokens [4w,4w+4), lane = expert
  const float Se  = ws[L];
  const float inv = ws[kE + L];
  #pragma unroll
  for (int tl = 0; tl < 4; ++tl) {
    int tk = w * 4 + tl;
    float Sx = sSxP[0][tk] + sSxP[1][tk] + sSxP[2][tk] + sSxP[3][tk];
    float Sq = sSxxP[0][tk] + sSxxP[1][tk] + sSxxP[2][tk] + sSxxP[3][tk];
    float mu   = Sx * (1.f / kD);
    float var  = Sq * (1.f / kD) - mu * mu;
    float rstd = rsqrtf(var + 1e-5f);
    float logit = (sLogit[tk * 68 + L] - mu * Se) * rstd * inv * 0.125f;

    float v1 = logit; int i1 = L;
    #pragma unroll
    for (int off = 32; off >= 1; off >>= 1) {
      float ov = __shfl_xor(v1, off, 64);
      int   oi = __shfl_xor(i1, off, 64);
      if (ov > v1 || (ov == v1 && oi < i1)) { v1 = ov; i1 = oi; }
    }
    float ml = (L == i1) ? -3.402823466e38f : logit;
    float v2 = ml; int i2 = L;
    #pragma unroll
    for (int off = 32; off >= 1; off >>= 1) {
      float ov = __shfl_xor(v2, off, 64);
      int   oi = __shfl_xor(i2, off, 64);
      if (ov > v2 || (ov == v2 && oi < i2)) { v2 = ov; i2 = oi; }
    }
    if (L == 0) {
      int tg = tok0 + tk;
      float er = expf(v2 - v1);
      float r  = 1.f / (1.f + er);
      out_w[2 * tg]     = r;
      out_w[2 * tg + 1] = er * r;
      out_i[2 * tg]     = (float)i1;   // harness reads whole buffer as f32
      out_i[2 * tg + 1] = (float)i2;
    }
  }
}

extern "C" void kernel_launch(void* const* d_in, const int* in_sizes, int n_in,
                              void* d_out, int out_size, void* d_ws, size_t ws_size,
                              hipStream_t stream) {
  const float* x = (const float*)d_in[0];   // [4,4096,2048] fp32
  const float* p = (const float*)d_in[1];   // [64,2048] fp32
  float* ws = (float*)d_ws;                 // 128 floats
  const int T = in_sizes[0] / kD;           // 16384 tokens
  float* out_w = (float*)d_out;
  float* out_i = (float*)d_out + (size_t)T * 2;

  proto_prep<<<kE, 256, 0, stream>>>(p, ws);
  router_main<<<T / kM, 256, 0, stream>>>(x, ws, out_w, out_i);
}